// Round 10
// baseline (72.550 us; speedup 1.0000x reference)
//
#include <hip/hip_runtime.h>
#include <hip/hip_bf16.h>
#include <float.h>
#include <limits.h>

#define FEAT    256
#define GAMMA_F 0.1f
#define EPS_F   1e-8f
#define KSEL    64        // BUDGET
#define NBUCK   4096      // 12-bit histogram of flipped-float keys
#define KSHIFT  20        // key >> KSHIFT -> bucket
#define CPW     8         // candidates per wave (8 KB of gathers in flight)
#define NB2     64        // select blocks
#define SLMAX   800       // max slice length (ceil(50000/64)=782)
#define BCAP    128       // per-block survivor region (expected ~98 used)
#define FCAP    2048      // LDS fallback capacity

// Monotonic float -> uint transform (ascending order preserved).
__device__ __forceinline__ unsigned key_of(float v) {
    unsigned u = __float_as_uint(v);
    return u ^ ((u >> 31) ? 0xFFFFFFFFu : 0x80000000u);
}

__device__ __forceinline__ bool comes_first(float va, int ia, float vb, int ib) {
    return (va > vb) || (va == vb && ia < ib);
}

// ---------------------------------------------------------------------------
// Kernel 1: edge scores. One-shot waves, CPW=8 (8 independent 1 KB gathers in
// flight/wave). Writes each score TWICE: to d_out (output; write-only, posted)
// and to a DEVICE-memory mirror in d_ws. Round-9 lesson: reads of d_out are
// ~10x-100x slower than device memory (62us select at 0.1% VALU) -- d_out is
// write-only everywhere from now on. Also zeroes the 2 ticket words.
// ---------------------------------------------------------------------------
__global__ __launch_bounds__(256) void edge_score_kernel(
    const float* __restrict__ infl,
    const float* __restrict__ feats,
    const int*   __restrict__ cand,
    const float* __restrict__ inj,
    float*       __restrict__ scores,   // d_out + KSEL (write-only)
    float*       __restrict__ mirror,   // d_ws device copy of scores
    unsigned*    __restrict__ zero2,    // done/oflow ticket words
    int num_cand)
{
    const int gtid = blockIdx.x * blockDim.x + threadIdx.x;
    if (gtid < 2) zero2[gtid] = 0u;

    const int lane = threadIdx.x & 63;
    const int wid  = gtid >> 6;
    const int base = wid * CPW;
    if (base >= num_cand) return;
    const int n_here = num_cand - base;   // >= 1

    const float4 g = *reinterpret_cast<const float4*>(inj + lane * 4);
    float ng = g.x * g.x + g.y * g.y + g.z * g.z + g.w * g.w;
    #pragma unroll
    for (int off = 32; off > 0; off >>= 1) ng += __shfl_xor(ng, off);
    const float inj_n = fmaxf(sqrtf(ng), EPS_F);

    float4 f[CPW];
    #pragma unroll
    for (int k = 0; k < CPW; ++k) {
        const int idx = base + ((k < n_here) ? k : 0);
        const int row = cand[idx];     // wave-uniform -> SGPR
        f[k] = *reinterpret_cast<const float4*>(feats + (size_t)row * FEAT + lane * 4);
    }

    float dot[CPW], nf[CPW];
    #pragma unroll
    for (int k = 0; k < CPW; ++k) {
        dot[k] = f[k].x * g.x + f[k].y * g.y + f[k].z * g.z + f[k].w * g.w;
        nf[k]  = f[k].x * f[k].x + f[k].y * f[k].y + f[k].z * f[k].z + f[k].w * f[k].w;
    }
    #pragma unroll
    for (int off = 32; off > 0; off >>= 1) {
        #pragma unroll
        for (int k = 0; k < CPW; ++k) {
            dot[k] += __shfl_xor(dot[k], off);
            nf[k]  += __shfl_xor(nf[k],  off);
        }
    }

    if (lane == 0) {
        if (n_here >= CPW) {
            const float4 i0 = *reinterpret_cast<const float4*>(infl + base);
            const float4 i1 = *reinterpret_cast<const float4*>(infl + base + 4);
            const float iv[8] = {i0.x, i0.y, i0.z, i0.w, i1.x, i1.y, i1.z, i1.w};
            float s[8];
            #pragma unroll
            for (int k = 0; k < 8; ++k)
                s[k] = iv[k] - GAMMA_F * (dot[k] / (fmaxf(sqrtf(nf[k]), EPS_F) * inj_n));
            const float4 a = make_float4(s[0], s[1], s[2], s[3]);
            const float4 b = make_float4(s[4], s[5], s[6], s[7]);
            *reinterpret_cast<float4*>(scores + base)     = a;
            *reinterpret_cast<float4*>(scores + base + 4) = b;
            *reinterpret_cast<float4*>(mirror + base)     = a;
            *reinterpret_cast<float4*>(mirror + base + 4) = b;
        } else {
            #pragma unroll
            for (int k = 0; k < CPW; ++k) {   // static indexing (scratch rule)
                if (k < n_here) {
                    const float s = infl[base + k]
                        - GAMMA_F * (dot[k] / (fmaxf(sqrtf(nf[k]), EPS_F) * inj_n));
                    scores[base + k] = s;
                    mirror[base + k] = s;
                }
            }
        }
    }
}

// ---------------------------------------------------------------------------
// Kernel 2: full selection, 64 blocks, reads ONLY the device mirror. Block b:
//   1. load its ~782-score slice into LDS (single coalesced global pass);
//   2. LDS hist + suffix-scan -> local bucket threshold B_b (any global
//      top-64 element in slice b is within slice b's local top-64);
//   3. compact survivors (~98) into a private global region (plain stores);
//   4. last-finished block (ticket): hist the ~6.3K region survivors,
//      global threshold B2, compact to ~90, bitonic-256, write top-64.
// Tie-pathology fallbacks (never expected) preserved from round 9.
// ---------------------------------------------------------------------------
__global__ __launch_bounds__(256) void select_kernel(
    const float* __restrict__ mirror,
    unsigned*    __restrict__ counts,      // [NB2]
    unsigned*    __restrict__ ticket,      // [0]=done, [1]=oflow
    float*       __restrict__ ws_v,        // [NB2*BCAP]
    int*         __restrict__ ws_i,        // [NB2*BCAP]
    const int*   __restrict__ cand,
    float*       __restrict__ out,         // d_out[0..KSEL) (write-only)
    int n)
{
    __shared__ float    sval[SLMAX];
    __shared__ unsigned h[NBUCK];
    __shared__ unsigned csum[256];
    __shared__ unsigned sB, sCnt;
    __shared__ int      sLast;
    __shared__ unsigned soff[NB2 + 1];
    __shared__ float    sv[FCAP];
    __shared__ int      si[FCAP];
    __shared__ float    wv[4];
    __shared__ int      wbi[4];

    const int t   = threadIdx.x;
    const int bid = blockIdx.x;
    const int SL  = (n + NB2 - 1) / NB2;
    const int lo  = bid * SL;
    const int hi  = min(n, lo + SL);
    const int cnt_here = max(hi - lo, 0);

    // --- 1. slice -> LDS (the only global read of the scores) ---
    for (int j = t; j < cnt_here; j += 256) sval[j] = mirror[lo + j];
    for (int i = t; i < NBUCK; i += 256) h[i] = 0;
    __syncthreads();

    // --- 2. LDS hist + local threshold ---
    for (int j = t; j < cnt_here; j += 256)
        atomicAdd(&h[key_of(sval[j]) >> KSHIFT], 1u);
    __syncthreads();
    {
        const int hb = NBUCK - 16 * t;     // chunk t = buckets [hb-16, hb)
        unsigned s = 0;
        for (int b = hb - 16; b < hb; ++b) s += h[b];
        csum[t] = s;
    }
    __syncthreads();
    if (t == 0) {
        const unsigned need = (unsigned)min(KSEL, cnt_here);
        unsigned cum = 0;
        int tc = 0;
        for (; tc < 256; ++tc) {
            if (cum + csum[tc] >= need) break;
            cum += csum[tc];
        }
        unsigned B = 0;
        if (tc < 256) {
            int b = NBUCK - 16 * tc - 1;
            for (int k = 0; k < 16; ++k, --b) {
                cum += h[b];
                if (cum >= need) { B = (unsigned)b; break; }
            }
        }
        sB = B;
        sCnt = 0;
    }
    __syncthreads();
    const unsigned B = sB;

    // --- 3. compact slice survivors into private region (plain stores) ---
    for (int j = t; j < cnt_here; j += 256) {
        const float v = sval[j];
        if ((key_of(v) >> KSHIFT) >= B) {
            const unsigned p = atomicAdd(&sCnt, 1u);   // LDS atomic
            if (p < BCAP) { ws_v[bid * BCAP + p] = v; ws_i[bid * BCAP + p] = lo + j; }
        }
    }
    __syncthreads();
    if (t == 0) {
        counts[bid] = min(sCnt, (unsigned)BCAP);
        if (sCnt > BCAP) atomicAdd(&ticket[1], 1u);    // never expected
    }

    // --- ticket: last-finished block runs the tail ---
    __threadfence();
    __syncthreads();
    if (t == 0) sLast = (atomicAdd(&ticket[0], 1u) == (unsigned)(NB2 - 1));
    __syncthreads();
    if (!sLast) return;
    __threadfence();

    bool desperate = (ticket[1] != 0u);
    int m = 0;

    if (!desperate) {
        if (t == 0) {
            unsigned acc = 0;
            #pragma unroll
            for (int r = 0; r < NB2; ++r) { soff[r] = acc; acc += counts[r]; }
            soff[NB2] = acc;
        }
        __syncthreads();
        const int S = (int)soff[NB2];   // ~6.3K survivors

        // hist the survivors
        for (int i = t; i < NBUCK; i += 256) h[i] = 0;
        __syncthreads();
        for (int idx = t; idx < NB2 * BCAP; idx += 256) {
            const int r = idx / BCAP, j = idx % BCAP;
            if ((unsigned)j < counts[r])
                atomicAdd(&h[key_of(ws_v[r * BCAP + j]) >> KSHIFT], 1u);
        }
        __syncthreads();
        {
            const int hb = NBUCK - 16 * t;
            unsigned s = 0;
            for (int b = hb - 16; b < hb; ++b) s += h[b];
            csum[t] = s;
        }
        __syncthreads();
        if (t == 0) {
            const unsigned need = (unsigned)min(KSEL, S);
            unsigned cum = 0;
            int tc = 0;
            for (; tc < 256; ++tc) {
                if (cum + csum[tc] >= need) break;
                cum += csum[tc];
            }
            unsigned B2 = 0;
            if (tc < 256) {
                int b = NBUCK - 16 * tc - 1;
                for (int k = 0; k < 16; ++k, --b) {
                    cum += h[b];
                    if (cum >= need) { B2 = (unsigned)b; break; }
                }
            }
            sB = B2;
            sCnt = 0;
        }
        __syncthreads();
        const unsigned B2 = sB;

        // compact globally-thresholded survivors into LDS
        for (int idx = t; idx < NB2 * BCAP; idx += 256) {
            const int r = idx / BCAP, j = idx % BCAP;
            if ((unsigned)j < counts[r]) {
                const float v = ws_v[r * BCAP + j];
                if ((key_of(v) >> KSHIFT) >= B2) {
                    const unsigned p = atomicAdd(&sCnt, 1u);
                    if (p < FCAP) { sv[p] = v; si[p] = ws_i[r * BCAP + j]; }
                }
            }
        }
        __syncthreads();
        if (sCnt > FCAP) desperate = true;             // tie pathology
        m = (int)min(sCnt, (unsigned)FCAP);
        __syncthreads();
    }

    if (desperate) {
        // Ultra-safe path: KSEL sequential global argmaxes over the mirror.
        __shared__ float sPv; __shared__ int sPi;
        if (t == 0) { sPv = INFINITY; sPi = -1; }
        __syncthreads();
        for (int k = 0; k < KSEL; ++k) {
            const float pv = sPv; const int pi = sPi;
            float bv = -INFINITY; int bi = INT_MAX;
            for (int i = t; i < n; i += 256) {
                const float v = mirror[i];
                if (comes_first(pv, pi, v, i) && comes_first(v, i, bv, bi)) { bv = v; bi = i; }
            }
            #pragma unroll
            for (int off = 32; off > 0; off >>= 1) {
                const float ov = __shfl_xor(bv, off);
                const int   oi = __shfl_xor(bi, off);
                if (comes_first(ov, oi, bv, bi)) { bv = ov; bi = oi; }
            }
            const int w = t >> 6;
            if ((t & 63) == 0) { wv[w] = bv; wbi[w] = bi; }
            __syncthreads();
            if (t == 0) {
                float fv = wv[0]; int fi = wbi[0];
                #pragma unroll
                for (int j = 1; j < 4; ++j)
                    if (comes_first(wv[j], wbi[j], fv, fi)) { fv = wv[j]; fi = wbi[j]; }
                out[k] = (float)cand[fi];
                sPv = fv; sPi = fi;
            }
            __syncthreads();
        }
        return;
    }

    if (m <= 256) {
        // bitonic sort of 256 slots: value desc, index asc (lax.top_k order)
        if (t >= m) { sv[t] = -INFINITY; si[t] = INT_MAX; }
        __syncthreads();
        for (int k = 2; k <= 256; k <<= 1) {
            for (int j = k >> 1; j > 0; j >>= 1) {
                const int p = t ^ j;
                if (p > t) {
                    const float va = sv[t], vb = sv[p];
                    const int   ia = si[t], ib = si[p];
                    const bool asc = ((t & k) == 0);
                    const bool doSwap = asc ? comes_first(vb, ib, va, ia)
                                            : comes_first(va, ia, vb, ib);
                    if (doSwap) { sv[t] = vb; si[t] = ib; sv[p] = va; si[p] = ia; }
                }
                __syncthreads();
            }
        }
        if (t < KSEL) out[t] = (float)cand[si[t]];
        return;
    }

    // Serial argmax over m <= FCAP LDS survivors (never expected).
    for (int i = t + m; i < FCAP; i += 256) { sv[i] = -INFINITY; si[i] = INT_MAX; }
    __syncthreads();
    for (int k = 0; k < KSEL; ++k) {
        float bv = -INFINITY; int bi = INT_MAX; int bs = 0;
        for (int i = t; i < FCAP; i += 256) {
            if (comes_first(sv[i], si[i], bv, bi)) { bv = sv[i]; bi = si[i]; bs = i; }
        }
        int bsv = bs;
        #pragma unroll
        for (int off = 32; off > 0; off >>= 1) {
            const float ov = __shfl_xor(bv, off);
            const int   oi = __shfl_xor(bi, off);
            const int   os = __shfl_xor(bsv, off);
            if (comes_first(ov, oi, bv, bi)) { bv = ov; bi = oi; bsv = os; }
        }
        const int w = t >> 6;
        if ((t & 63) == 0) { wv[w] = bv; wbi[w] = bi; csum[w] = (unsigned)bsv; }
        __syncthreads();
        if (t == 0) {
            float fv = wv[0]; int fi = wbi[0]; int fs = (int)csum[0];
            #pragma unroll
            for (int j = 1; j < 4; ++j)
                if (comes_first(wv[j], wbi[j], fv, fi)) { fv = wv[j]; fi = wbi[j]; fs = (int)csum[j]; }
            out[k] = (float)cand[fi];
            sv[fs] = -INFINITY;
            si[fs] = INT_MAX;
        }
        __syncthreads();
    }
}

extern "C" void kernel_launch(void* const* d_in, const int* in_sizes, int n_in,
                              void* d_out, int out_size, void* d_ws, size_t ws_size,
                              hipStream_t stream) {
    const float* infl  = (const float*)d_in[0];   // [num_cand]
    const float* feats = (const float*)d_in[1];   // [num_nodes, 256]
    const int*   cand  = (const int*)d_in[2];     // [num_cand]
    const float* inj   = (const float*)d_in[3];   // [256]

    const int num_cand = in_sizes[0];

    float* out    = (float*)d_out;          // [0..64): indices-as-f32 (write-only)
    float* scores = (float*)d_out + KSEL;   // [64..): edge scores (write-only)

    unsigned* ws_counts = (unsigned*)d_ws;                // NB2
    unsigned* ws_ticket = ws_counts + NB2;                // 2 (done, oflow)
    float*    ws_v      = (float*)(ws_ticket + 2);        // NB2*BCAP
    int*      ws_i      = (int*)(ws_v + NB2 * BCAP);      // NB2*BCAP
    float*    ws_mirror = (float*)(ws_i + NB2 * BCAP);    // num_cand (device copy)

    // 1. Edge scores -> d_out + device mirror (zeroes the 2 ticket words).
    {
        const int waves  = (num_cand + CPW - 1) / CPW;
        const int blocks = (waves + 3) / 4;
        edge_score_kernel<<<blocks, 256, 0, stream>>>(
            infl, feats, cand, inj, scores, ws_mirror, ws_ticket, num_cand);
    }

    // 2. Full selection from the mirror (never reads d_out).
    select_kernel<<<NB2, 256, 0, stream>>>(
        ws_mirror, ws_counts, ws_ticket, ws_v, ws_i, cand, out, num_cand);
}

// Round 11
// 66.517 us; speedup vs baseline: 1.0907x; 1.0907x over previous
//
#include <hip/hip_runtime.h>
#include <hip/hip_bf16.h>
#include <float.h>
#include <limits.h>

#define FEAT    256
#define GAMMA_F 0.1f
#define EPS_F   1e-8f
#define KSEL    64        // BUDGET
#define NBUCK   4096      // 12-bit histogram of flipped-float keys
#define KSHIFT  20        // key >> KSHIFT -> bucket
#define CPW     8         // candidates per wave (8 KB of gathers in flight)
#define NB2     64        // slice blocks
#define SLMAX   800       // max slice length (ceil(50000/64)=782)
#define BCAP    128       // per-block survivor region (expected ~79 used)
#define FCAP    2048      // LDS fallback capacity

// Monotonic float -> uint transform (ascending order preserved).
__device__ __forceinline__ unsigned key_of(float v) {
    unsigned u = __float_as_uint(v);
    return u ^ ((u >> 31) ? 0xFFFFFFFFu : 0x80000000u);
}

__device__ __forceinline__ bool comes_first(float va, int ia, float vb, int ib) {
    return (va > vb) || (va == vb && ia < ib);
}

// ---------------------------------------------------------------------------
// Kernel 1: edge scores (unchanged from R9/R10: measured ~6-7 us). One-shot
// waves, CPW=8. Writes scores to d_out (write-only) and to the d_ws mirror.
// No ticket words to zero anymore -- downstream kernels need NO pre-zeroed
// state (R10 lesson: device-fence/ticket tails cost ~55 us of idle; kernel
// boundaries give the same ordering for free).
// ---------------------------------------------------------------------------
__global__ __launch_bounds__(256) void edge_score_kernel(
    const float* __restrict__ infl,
    const float* __restrict__ feats,
    const int*   __restrict__ cand,
    const float* __restrict__ inj,
    float*       __restrict__ scores,   // d_out + KSEL (write-only)
    float*       __restrict__ mirror,   // d_ws device copy of scores
    int num_cand)
{
    const int gtid = blockIdx.x * blockDim.x + threadIdx.x;
    const int lane = threadIdx.x & 63;
    const int wid  = gtid >> 6;
    const int base = wid * CPW;
    if (base >= num_cand) return;
    const int n_here = num_cand - base;   // >= 1

    const float4 g = *reinterpret_cast<const float4*>(inj + lane * 4);
    float ng = g.x * g.x + g.y * g.y + g.z * g.z + g.w * g.w;
    #pragma unroll
    for (int off = 32; off > 0; off >>= 1) ng += __shfl_xor(ng, off);
    const float inj_n = fmaxf(sqrtf(ng), EPS_F);

    float4 f[CPW];
    #pragma unroll
    for (int k = 0; k < CPW; ++k) {
        const int idx = base + ((k < n_here) ? k : 0);
        const int row = cand[idx];     // wave-uniform -> SGPR
        f[k] = *reinterpret_cast<const float4*>(feats + (size_t)row * FEAT + lane * 4);
    }

    float dot[CPW], nf[CPW];
    #pragma unroll
    for (int k = 0; k < CPW; ++k) {
        dot[k] = f[k].x * g.x + f[k].y * g.y + f[k].z * g.z + f[k].w * g.w;
        nf[k]  = f[k].x * f[k].x + f[k].y * f[k].y + f[k].z * f[k].z + f[k].w * f[k].w;
    }
    #pragma unroll
    for (int off = 32; off > 0; off >>= 1) {
        #pragma unroll
        for (int k = 0; k < CPW; ++k) {
            dot[k] += __shfl_xor(dot[k], off);
            nf[k]  += __shfl_xor(nf[k],  off);
        }
    }

    if (lane == 0) {
        if (n_here >= CPW) {
            const float4 i0 = *reinterpret_cast<const float4*>(infl + base);
            const float4 i1 = *reinterpret_cast<const float4*>(infl + base + 4);
            const float iv[8] = {i0.x, i0.y, i0.z, i0.w, i1.x, i1.y, i1.z, i1.w};
            float s[8];
            #pragma unroll
            for (int k = 0; k < 8; ++k)
                s[k] = iv[k] - GAMMA_F * (dot[k] / (fmaxf(sqrtf(nf[k]), EPS_F) * inj_n));
            const float4 a = make_float4(s[0], s[1], s[2], s[3]);
            const float4 b = make_float4(s[4], s[5], s[6], s[7]);
            *reinterpret_cast<float4*>(scores + base)     = a;
            *reinterpret_cast<float4*>(scores + base + 4) = b;
            *reinterpret_cast<float4*>(mirror + base)     = a;
            *reinterpret_cast<float4*>(mirror + base + 4) = b;
        } else {
            #pragma unroll
            for (int k = 0; k < CPW; ++k) {   // static indexing (scratch rule)
                if (k < n_here) {
                    const float s = infl[base + k]
                        - GAMMA_F * (dot[k] / (fmaxf(sqrtf(nf[k]), EPS_F) * inj_n));
                    scores[base + k] = s;
                    mirror[base + k] = s;
                }
            }
        }
    }
}

// ---------------------------------------------------------------------------
// Kernel 2a: per-slice filter, 64 blocks, NO device-scope sync of any kind.
// Block b: slice -> LDS; LDS hist; local bucket threshold B_b (the slice's
// local top-64 is a superset of global-top-64 ∩ slice); compact survivors
// into a private region with plain stores; publish the UNCLAMPED count
// (overflow detectable downstream without pre-zeroed flags).
// ---------------------------------------------------------------------------
__global__ __launch_bounds__(256) void slice_filter_kernel(
    const float* __restrict__ mirror,
    unsigned*    __restrict__ counts,      // [NB2], unclamped
    float*       __restrict__ ws_v,        // [NB2*BCAP]
    int*         __restrict__ ws_i,        // [NB2*BCAP]
    int n)
{
    __shared__ float    sval[SLMAX];
    __shared__ unsigned h[NBUCK];
    __shared__ unsigned csum[256];
    __shared__ unsigned sB, sCnt;

    const int t   = threadIdx.x;
    const int bid = blockIdx.x;
    const int SL  = (n + NB2 - 1) / NB2;
    const int lo  = bid * SL;
    const int hi  = min(n, lo + SL);
    const int cnt_here = max(hi - lo, 0);

    // slice -> LDS (single coalesced read of this block's scores)
    for (int j = t; j < cnt_here; j += 256) sval[j] = mirror[lo + j];
    for (int i = t; i < NBUCK; i += 256) h[i] = 0;
    __syncthreads();

    // LDS hist + local threshold
    for (int j = t; j < cnt_here; j += 256)
        atomicAdd(&h[key_of(sval[j]) >> KSHIFT], 1u);
    __syncthreads();
    {
        const int hb = NBUCK - 16 * t;     // chunk t = buckets [hb-16, hb)
        unsigned s = 0;
        for (int b = hb - 16; b < hb; ++b) s += h[b];
        csum[t] = s;
    }
    __syncthreads();
    if (t == 0) {
        const unsigned need = (unsigned)min(KSEL, cnt_here);
        unsigned cum = 0;
        int tc = 0;
        for (; tc < 256; ++tc) {
            if (cum + csum[tc] >= need) break;
            cum += csum[tc];
        }
        unsigned B = 0;
        if (tc < 256) {
            int b = NBUCK - 16 * tc - 1;
            for (int k = 0; k < 16; ++k, --b) {
                cum += h[b];
                if (cum >= need) { B = (unsigned)b; break; }
            }
        }
        sB = B;
        sCnt = 0;
    }
    __syncthreads();
    const unsigned B = sB;

    // compact survivors into private region (plain stores, LDS counter)
    for (int j = t; j < cnt_here; j += 256) {
        const float v = sval[j];
        if ((key_of(v) >> KSHIFT) >= B) {
            const unsigned p = atomicAdd(&sCnt, 1u);
            if (p < BCAP) { ws_v[bid * BCAP + p] = v; ws_i[bid * BCAP + p] = lo + j; }
        }
    }
    __syncthreads();
    if (t == 0) counts[bid] = sCnt;   // unclamped; K2b clamps + detects oflow
}

// ---------------------------------------------------------------------------
// Kernel 2b: final top-64, ONE block over tiny data (~5K survivors, 40 KB).
// Ordering with K2a comes from the kernel boundary -- no fence/ticket.
// Assemble regions via serial prefix, hist survivors, global threshold B2,
// compact to ~120, bitonic-256 (value desc, index asc), write indices.
// Fallbacks: LDS serial-argmax (m<=FCAP), else 64x global argmax (oflow).
// ---------------------------------------------------------------------------
__global__ __launch_bounds__(256) void final_topk_kernel(
    const float* __restrict__ mirror,
    const unsigned* __restrict__ counts,   // [NB2]
    const float* __restrict__ ws_v,        // [NB2*BCAP]
    const int*   __restrict__ ws_i,        // [NB2*BCAP]
    const int*   __restrict__ cand,
    float*       __restrict__ out,         // d_out[0..KSEL) (write-only)
    int n)
{
    __shared__ unsigned h[NBUCK];
    __shared__ unsigned csum[256];
    __shared__ unsigned sB, sCnt;
    __shared__ unsigned soff[NB2 + 1];
    __shared__ int      sOflow;
    __shared__ float    sv[FCAP];
    __shared__ int      si[FCAP];
    __shared__ float    wv[4];
    __shared__ int      wbi[4];

    const int t = threadIdx.x;

    // prefix offsets over region counts; detect overflow
    if (t == 0) {
        unsigned acc = 0;
        int of = 0;
        #pragma unroll
        for (int r = 0; r < NB2; ++r) {
            const unsigned c = counts[r];
            if (c > BCAP) of = 1;
            soff[r] = acc;
            acc += min(c, (unsigned)BCAP);
        }
        soff[NB2] = acc;
        sOflow = of;
        sCnt = 0;
    }
    __syncthreads();
    bool desperate = (sOflow != 0);
    int m = 0;

    if (!desperate) {
        const int S = (int)soff[NB2];   // ~5K survivors

        // hist the survivors
        for (int i = t; i < NBUCK; i += 256) h[i] = 0;
        __syncthreads();
        for (int idx = t; idx < NB2 * BCAP; idx += 256) {
            const int r = idx >> 7, j = idx & (BCAP - 1);
            if ((unsigned)j < min(counts[r], (unsigned)BCAP))
                atomicAdd(&h[key_of(ws_v[idx]) >> KSHIFT], 1u);
        }
        __syncthreads();
        {
            const int hb = NBUCK - 16 * t;
            unsigned s = 0;
            for (int b = hb - 16; b < hb; ++b) s += h[b];
            csum[t] = s;
        }
        __syncthreads();
        if (t == 0) {
            const unsigned need = (unsigned)min(KSEL, S);
            unsigned cum = 0;
            int tc = 0;
            for (; tc < 256; ++tc) {
                if (cum + csum[tc] >= need) break;
                cum += csum[tc];
            }
            unsigned B2 = 0;
            if (tc < 256) {
                int b = NBUCK - 16 * tc - 1;
                for (int k = 0; k < 16; ++k, --b) {
                    cum += h[b];
                    if (cum >= need) { B2 = (unsigned)b; break; }
                }
            }
            sB = B2;
        }
        __syncthreads();
        const unsigned B2 = sB;

        // compact globally-thresholded survivors into LDS
        for (int idx = t; idx < NB2 * BCAP; idx += 256) {
            const int r = idx >> 7, j = idx & (BCAP - 1);
            if ((unsigned)j < min(counts[r], (unsigned)BCAP)) {
                const float v = ws_v[idx];
                if ((key_of(v) >> KSHIFT) >= B2) {
                    const unsigned p = atomicAdd(&sCnt, 1u);
                    if (p < FCAP) { sv[p] = v; si[p] = ws_i[idx]; }
                }
            }
        }
        __syncthreads();
        if (sCnt > FCAP) desperate = true;             // tie pathology
        m = (int)min(sCnt, (unsigned)FCAP);
        __syncthreads();
    }

    if (desperate) {
        // Ultra-safe path: KSEL sequential global argmaxes over the mirror.
        __shared__ float sPv; __shared__ int sPi;
        if (t == 0) { sPv = INFINITY; sPi = -1; }
        __syncthreads();
        for (int k = 0; k < KSEL; ++k) {
            const float pv = sPv; const int pi = sPi;
            float bv = -INFINITY; int bi = INT_MAX;
            for (int i = t; i < n; i += 256) {
                const float v = mirror[i];
                if (comes_first(pv, pi, v, i) && comes_first(v, i, bv, bi)) { bv = v; bi = i; }
            }
            #pragma unroll
            for (int off = 32; off > 0; off >>= 1) {
                const float ov = __shfl_xor(bv, off);
                const int   oi = __shfl_xor(bi, off);
                if (comes_first(ov, oi, bv, bi)) { bv = ov; bi = oi; }
            }
            const int w = t >> 6;
            if ((t & 63) == 0) { wv[w] = bv; wbi[w] = bi; }
            __syncthreads();
            if (t == 0) {
                float fv = wv[0]; int fi = wbi[0];
                #pragma unroll
                for (int j = 1; j < 4; ++j)
                    if (comes_first(wv[j], wbi[j], fv, fi)) { fv = wv[j]; fi = wbi[j]; }
                out[k] = (float)cand[fi];
                sPv = fv; sPi = fi;
            }
            __syncthreads();
        }
        return;
    }

    if (m <= 256) {
        // bitonic sort of 256 slots: value desc, index asc (lax.top_k order)
        if (t >= m) { sv[t] = -INFINITY; si[t] = INT_MAX; }
        __syncthreads();
        for (int k = 2; k <= 256; k <<= 1) {
            for (int j = k >> 1; j > 0; j >>= 1) {
                const int p = t ^ j;
                if (p > t) {
                    const float va = sv[t], vb = sv[p];
                    const int   ia = si[t], ib = si[p];
                    const bool asc = ((t & k) == 0);
                    const bool doSwap = asc ? comes_first(vb, ib, va, ia)
                                            : comes_first(va, ia, vb, ib);
                    if (doSwap) { sv[t] = vb; si[t] = ib; sv[p] = va; si[p] = ia; }
                }
                __syncthreads();
            }
        }
        if (t < KSEL) out[t] = (float)cand[si[t]];
        return;
    }

    // Serial argmax over m <= FCAP LDS survivors (never expected).
    for (int i = t + m; i < FCAP; i += 256) { sv[i] = -INFINITY; si[i] = INT_MAX; }
    __syncthreads();
    for (int k = 0; k < KSEL; ++k) {
        float bv = -INFINITY; int bi = INT_MAX; int bs = 0;
        for (int i = t; i < FCAP; i += 256) {
            if (comes_first(sv[i], si[i], bv, bi)) { bv = sv[i]; bi = si[i]; bs = i; }
        }
        int bsv = bs;
        #pragma unroll
        for (int off = 32; off > 0; off >>= 1) {
            const float ov = __shfl_xor(bv, off);
            const int   oi = __shfl_xor(bi, off);
            const int   os = __shfl_xor(bsv, off);
            if (comes_first(ov, oi, bv, bi)) { bv = ov; bi = oi; bsv = os; }
        }
        const int w = t >> 6;
        if ((t & 63) == 0) { wv[w] = bv; wbi[w] = bi; csum[w] = (unsigned)bsv; }
        __syncthreads();
        if (t == 0) {
            float fv = wv[0]; int fi = wbi[0]; int fs = (int)csum[0];
            #pragma unroll
            for (int j = 1; j < 4; ++j)
                if (comes_first(wv[j], wbi[j], fv, fi)) { fv = wv[j]; fi = wbi[j]; fs = (int)csum[j]; }
            out[k] = (float)cand[fi];
            sv[fs] = -INFINITY;
            si[fs] = INT_MAX;
        }
        __syncthreads();
    }
}

extern "C" void kernel_launch(void* const* d_in, const int* in_sizes, int n_in,
                              void* d_out, int out_size, void* d_ws, size_t ws_size,
                              hipStream_t stream) {
    const float* infl  = (const float*)d_in[0];   // [num_cand]
    const float* feats = (const float*)d_in[1];   // [num_nodes, 256]
    const int*   cand  = (const int*)d_in[2];     // [num_cand]
    const float* inj   = (const float*)d_in[3];   // [256]

    const int num_cand = in_sizes[0];

    float* out    = (float*)d_out;          // [0..64): indices-as-f32 (write-only)
    float* scores = (float*)d_out + KSEL;   // [64..): edge scores (write-only)

    unsigned* ws_counts = (unsigned*)d_ws;                // NB2
    float*    ws_v      = (float*)(ws_counts + NB2);      // NB2*BCAP
    int*      ws_i      = (int*)(ws_v + NB2 * BCAP);      // NB2*BCAP
    float*    ws_mirror = (float*)(ws_i + NB2 * BCAP);    // num_cand

    // 1. Edge scores -> d_out + device mirror (~7 us, measured R9/R10).
    {
        const int waves  = (num_cand + CPW - 1) / CPW;
        const int blocks = (waves + 3) / 4;
        edge_score_kernel<<<blocks, 256, 0, stream>>>(
            infl, feats, cand, inj, scores, ws_mirror, num_cand);
    }

    // 2a. Per-slice local-threshold filter (no fences, no tickets).
    slice_filter_kernel<<<NB2, 256, 0, stream>>>(
        ws_mirror, ws_counts, ws_v, ws_i, num_cand);

    // 2b. Final exact top-64 over ~5K survivors (1 block, tiny data).
    final_topk_kernel<<<1, 256, 0, stream>>>(
        ws_mirror, ws_counts, ws_v, ws_i, cand, out, num_cand);
}

// Round 12
// 65.571 us; speedup vs baseline: 1.1064x; 1.0144x over previous
//
#include <hip/hip_runtime.h>
#include <hip/hip_bf16.h>
#include <float.h>
#include <limits.h>

#define FEAT    256
#define GAMMA_F 0.1f
#define EPS_F   1e-8f
#define KSEL    64        // BUDGET
#define NBUCK   4096      // 12-bit histogram of flipped-float keys
#define KSHIFT  20        // key >> KSHIFT -> bucket
#define NB1     1024      // persistent score blocks (4096 waves) -- R6 config
#define CPW     4         // candidates per wave -- R6 config (CPW=8 correlates
                          // with the 66-74us rounds; likely VGPR/occupancy cliff)
#define NB2     64        // slice blocks
#define SLMAX   800       // max slice length (ceil(50000/64)=782)
#define BCAP    128       // per-block survivor region (expected ~90 used)
#define FCAP    2048      // LDS fallback capacity

// Monotonic float -> uint transform (ascending order preserved).
__device__ __forceinline__ unsigned key_of(float v) {
    unsigned u = __float_as_uint(v);
    return u ^ ((u >> 31) ? 0xFFFFFFFFu : 0x80000000u);
}

__device__ __forceinline__ bool comes_first(float va, int ia, float vb, int ib) {
    return (va > vb) || (va == vb && ia < ib);
}

// ---------------------------------------------------------------------------
// Kernel 1: edge scores -- EXACT round-6 structure (the fastest measured:
// 46.2us total). Persistent grid, 1024 blocks = 4096 waves, CPW=4 independent
// 1 KB row-gathers in flight per wave, ||inj|| hoisted, float4 score stores.
// Dual-writes scores to d_out (output, write-only) and the d_ws mirror.
// A/B note: R9-R11's one-shot CPW=8 variant correlates with +20us totals
// (suspect VGPR-driven occupancy step); this round isolates that variable.
// ---------------------------------------------------------------------------
__global__ __launch_bounds__(256) void edge_score_kernel(
    const float* __restrict__ infl,
    const float* __restrict__ feats,
    const int*   __restrict__ cand,
    const float* __restrict__ inj,
    float*       __restrict__ scores,   // d_out + KSEL (write-only)
    float*       __restrict__ mirror,   // d_ws device copy of scores
    int num_cand)
{
    const int gtid    = blockIdx.x * blockDim.x + threadIdx.x;
    const int lane    = threadIdx.x & 63;
    const int wid     = gtid >> 6;
    const int nwaves  = NB1 * 4;
    const int ngroups = (num_cand + CPW - 1) / CPW;

    const float4 g = *reinterpret_cast<const float4*>(inj + lane * 4);
    float ng = g.x * g.x + g.y * g.y + g.z * g.z + g.w * g.w;
    #pragma unroll
    for (int off = 32; off > 0; off >>= 1) ng += __shfl_xor(ng, off);
    const float inj_n = fmaxf(sqrtf(ng), EPS_F);

    for (int grp = wid; grp < ngroups; grp += nwaves) {
        const int base   = grp * CPW;
        const int n_here = num_cand - base;   // >= 1

        const int r0 = cand[base];
        const int r1 = (n_here > 1) ? cand[base + 1] : r0;
        const int r2 = (n_here > 2) ? cand[base + 2] : r0;
        const int r3 = (n_here > 3) ? cand[base + 3] : r0;
        const float4 f0 = *reinterpret_cast<const float4*>(feats + (size_t)r0 * FEAT + lane * 4);
        const float4 f1 = *reinterpret_cast<const float4*>(feats + (size_t)r1 * FEAT + lane * 4);
        const float4 f2 = *reinterpret_cast<const float4*>(feats + (size_t)r2 * FEAT + lane * 4);
        const float4 f3 = *reinterpret_cast<const float4*>(feats + (size_t)r3 * FEAT + lane * 4);

        float dot0 = f0.x*g.x + f0.y*g.y + f0.z*g.z + f0.w*g.w;
        float nf0  = f0.x*f0.x + f0.y*f0.y + f0.z*f0.z + f0.w*f0.w;
        float dot1 = f1.x*g.x + f1.y*g.y + f1.z*g.z + f1.w*g.w;
        float nf1  = f1.x*f1.x + f1.y*f1.y + f1.z*f1.z + f1.w*f1.w;
        float dot2 = f2.x*g.x + f2.y*g.y + f2.z*g.z + f2.w*g.w;
        float nf2  = f2.x*f2.x + f2.y*f2.y + f2.z*f2.z + f2.w*f2.w;
        float dot3 = f3.x*g.x + f3.y*g.y + f3.z*g.z + f3.w*g.w;
        float nf3  = f3.x*f3.x + f3.y*f3.y + f3.z*f3.z + f3.w*f3.w;

        #pragma unroll
        for (int off = 32; off > 0; off >>= 1) {
            dot0 += __shfl_xor(dot0, off);  nf0 += __shfl_xor(nf0, off);
            dot1 += __shfl_xor(dot1, off);  nf1 += __shfl_xor(nf1, off);
            dot2 += __shfl_xor(dot2, off);  nf2 += __shfl_xor(nf2, off);
            dot3 += __shfl_xor(dot3, off);  nf3 += __shfl_xor(nf3, off);
        }

        if (lane == 0) {
            const float s0 = infl[base] - GAMMA_F * (dot0 / (fmaxf(sqrtf(nf0), EPS_F) * inj_n));
            if (n_here >= 4) {
                const float s1 = infl[base+1] - GAMMA_F * (dot1 / (fmaxf(sqrtf(nf1), EPS_F) * inj_n));
                const float s2 = infl[base+2] - GAMMA_F * (dot2 / (fmaxf(sqrtf(nf2), EPS_F) * inj_n));
                const float s3 = infl[base+3] - GAMMA_F * (dot3 / (fmaxf(sqrtf(nf3), EPS_F) * inj_n));
                const float4 s4 = make_float4(s0, s1, s2, s3);
                *reinterpret_cast<float4*>(scores + base) = s4;
                *reinterpret_cast<float4*>(mirror + base) = s4;
            } else {
                scores[base] = s0;
                mirror[base] = s0;
                if (n_here > 1) {
                    const float s1 = infl[base+1] - GAMMA_F * (dot1 / (fmaxf(sqrtf(nf1), EPS_F) * inj_n));
                    scores[base+1] = s1;  mirror[base+1] = s1;
                }
                if (n_here > 2) {
                    const float s2 = infl[base+2] - GAMMA_F * (dot2 / (fmaxf(sqrtf(nf2), EPS_F) * inj_n));
                    scores[base+2] = s2;  mirror[base+2] = s2;
                }
            }
        }
    }
}

// ---------------------------------------------------------------------------
// Kernel 2a: per-slice filter, 64 blocks, no device-scope sync (R11). Block
// b: slice -> LDS; LDS hist; local bucket threshold B_b (slice's local top-64
// is a superset of global-top-64 ∩ slice); compact survivors into a private
// region with plain stores; publish the UNCLAMPED count.
// ---------------------------------------------------------------------------
__global__ __launch_bounds__(256) void slice_filter_kernel(
    const float* __restrict__ mirror,
    unsigned*    __restrict__ counts,      // [NB2], unclamped
    float*       __restrict__ ws_v,        // [NB2*BCAP]
    int*         __restrict__ ws_i,        // [NB2*BCAP]
    int n)
{
    __shared__ float    sval[SLMAX];
    __shared__ unsigned h[NBUCK];
    __shared__ unsigned csum[256];
    __shared__ unsigned sB, sCnt;

    const int t   = threadIdx.x;
    const int bid = blockIdx.x;
    const int SL  = (n + NB2 - 1) / NB2;
    const int lo  = bid * SL;
    const int hi  = min(n, lo + SL);
    const int cnt_here = max(hi - lo, 0);

    for (int j = t; j < cnt_here; j += 256) sval[j] = mirror[lo + j];
    for (int i = t; i < NBUCK; i += 256) h[i] = 0;
    __syncthreads();

    for (int j = t; j < cnt_here; j += 256)
        atomicAdd(&h[key_of(sval[j]) >> KSHIFT], 1u);
    __syncthreads();
    {
        const int hb = NBUCK - 16 * t;     // chunk t = buckets [hb-16, hb)
        unsigned s = 0;
        for (int b = hb - 16; b < hb; ++b) s += h[b];
        csum[t] = s;
    }
    __syncthreads();
    if (t == 0) {
        const unsigned need = (unsigned)min(KSEL, cnt_here);
        unsigned cum = 0;
        int tc = 0;
        for (; tc < 256; ++tc) {
            if (cum + csum[tc] >= need) break;
            cum += csum[tc];
        }
        unsigned B = 0;
        if (tc < 256) {
            int b = NBUCK - 16 * tc - 1;
            for (int k = 0; k < 16; ++k, --b) {
                cum += h[b];
                if (cum >= need) { B = (unsigned)b; break; }
            }
        }
        sB = B;
        sCnt = 0;
    }
    __syncthreads();
    const unsigned B = sB;

    for (int j = t; j < cnt_here; j += 256) {
        const float v = sval[j];
        if ((key_of(v) >> KSHIFT) >= B) {
            const unsigned p = atomicAdd(&sCnt, 1u);
            if (p < BCAP) { ws_v[bid * BCAP + p] = v; ws_i[bid * BCAP + p] = lo + j; }
        }
    }
    __syncthreads();
    if (t == 0) counts[bid] = sCnt;   // unclamped; K2b clamps + detects oflow
}

// ---------------------------------------------------------------------------
// Kernel 2b: final top-64, ONE block over tiny data (~5K survivors, 40 KB).
// Ordering via kernel boundary. Hist survivors, global threshold B2, compact
// to ~120, bitonic-256 (value desc, index asc), write indices. Fallbacks:
// LDS serial-argmax (m<=FCAP), else KSEL sequential global argmaxes.
// ---------------------------------------------------------------------------
__global__ __launch_bounds__(256) void final_topk_kernel(
    const float* __restrict__ mirror,
    const unsigned* __restrict__ counts,   // [NB2]
    const float* __restrict__ ws_v,        // [NB2*BCAP]
    const int*   __restrict__ ws_i,        // [NB2*BCAP]
    const int*   __restrict__ cand,
    float*       __restrict__ out,         // d_out[0..KSEL) (write-only)
    int n)
{
    __shared__ unsigned h[NBUCK];
    __shared__ unsigned csum[256];
    __shared__ unsigned sB, sCnt;
    __shared__ unsigned soff[NB2 + 1];
    __shared__ int      sOflow;
    __shared__ float    sv[FCAP];
    __shared__ int      si[FCAP];
    __shared__ float    wv[4];
    __shared__ int      wbi[4];

    const int t = threadIdx.x;

    if (t == 0) {
        unsigned acc = 0;
        int of = 0;
        #pragma unroll
        for (int r = 0; r < NB2; ++r) {
            const unsigned c = counts[r];
            if (c > BCAP) of = 1;
            soff[r] = acc;
            acc += min(c, (unsigned)BCAP);
        }
        soff[NB2] = acc;
        sOflow = of;
        sCnt = 0;
    }
    __syncthreads();
    bool desperate = (sOflow != 0);
    int m = 0;

    if (!desperate) {
        const int S = (int)soff[NB2];   // ~5K survivors

        for (int i = t; i < NBUCK; i += 256) h[i] = 0;
        __syncthreads();
        for (int idx = t; idx < NB2 * BCAP; idx += 256) {
            const int r = idx >> 7, j = idx & (BCAP - 1);
            if ((unsigned)j < min(counts[r], (unsigned)BCAP))
                atomicAdd(&h[key_of(ws_v[idx]) >> KSHIFT], 1u);
        }
        __syncthreads();
        {
            const int hb = NBUCK - 16 * t;
            unsigned s = 0;
            for (int b = hb - 16; b < hb; ++b) s += h[b];
            csum[t] = s;
        }
        __syncthreads();
        if (t == 0) {
            const unsigned need = (unsigned)min(KSEL, S);
            unsigned cum = 0;
            int tc = 0;
            for (; tc < 256; ++tc) {
                if (cum + csum[tc] >= need) break;
                cum += csum[tc];
            }
            unsigned B2 = 0;
            if (tc < 256) {
                int b = NBUCK - 16 * tc - 1;
                for (int k = 0; k < 16; ++k, --b) {
                    cum += h[b];
                    if (cum >= need) { B2 = (unsigned)b; break; }
                }
            }
            sB = B2;
        }
        __syncthreads();
        const unsigned B2 = sB;

        for (int idx = t; idx < NB2 * BCAP; idx += 256) {
            const int r = idx >> 7, j = idx & (BCAP - 1);
            if ((unsigned)j < min(counts[r], (unsigned)BCAP)) {
                const float v = ws_v[idx];
                if ((key_of(v) >> KSHIFT) >= B2) {
                    const unsigned p = atomicAdd(&sCnt, 1u);
                    if (p < FCAP) { sv[p] = v; si[p] = ws_i[idx]; }
                }
            }
        }
        __syncthreads();
        if (sCnt > FCAP) desperate = true;             // tie pathology
        m = (int)min(sCnt, (unsigned)FCAP);
        __syncthreads();
    }

    if (desperate) {
        // Ultra-safe path: KSEL sequential global argmaxes over the mirror.
        __shared__ float sPv; __shared__ int sPi;
        if (t == 0) { sPv = INFINITY; sPi = -1; }
        __syncthreads();
        for (int k = 0; k < KSEL; ++k) {
            const float pv = sPv; const int pi = sPi;
            float bv = -INFINITY; int bi = INT_MAX;
            for (int i = t; i < n; i += 256) {
                const float v = mirror[i];
                if (comes_first(pv, pi, v, i) && comes_first(v, i, bv, bi)) { bv = v; bi = i; }
            }
            #pragma unroll
            for (int off = 32; off > 0; off >>= 1) {
                const float ov = __shfl_xor(bv, off);
                const int   oi = __shfl_xor(bi, off);
                if (comes_first(ov, oi, bv, bi)) { bv = ov; bi = oi; }
            }
            const int w = t >> 6;
            if ((t & 63) == 0) { wv[w] = bv; wbi[w] = bi; }
            __syncthreads();
            if (t == 0) {
                float fv = wv[0]; int fi = wbi[0];
                #pragma unroll
                for (int j = 1; j < 4; ++j)
                    if (comes_first(wv[j], wbi[j], fv, fi)) { fv = wv[j]; fi = wbi[j]; }
                out[k] = (float)cand[fi];
                sPv = fv; sPi = fi;
            }
            __syncthreads();
        }
        return;
    }

    if (m <= 256) {
        if (t >= m) { sv[t] = -INFINITY; si[t] = INT_MAX; }
        __syncthreads();
        for (int k = 2; k <= 256; k <<= 1) {
            for (int j = k >> 1; j > 0; j >>= 1) {
                const int p = t ^ j;
                if (p > t) {
                    const float va = sv[t], vb = sv[p];
                    const int   ia = si[t], ib = si[p];
                    const bool asc = ((t & k) == 0);
                    const bool doSwap = asc ? comes_first(vb, ib, va, ia)
                                            : comes_first(va, ia, vb, ib);
                    if (doSwap) { sv[t] = vb; si[t] = ib; sv[p] = va; si[p] = ia; }
                }
                __syncthreads();
            }
        }
        if (t < KSEL) out[t] = (float)cand[si[t]];
        return;
    }

    // Serial argmax over m <= FCAP LDS survivors (never expected).
    for (int i = t + m; i < FCAP; i += 256) { sv[i] = -INFINITY; si[i] = INT_MAX; }
    __syncthreads();
    for (int k = 0; k < KSEL; ++k) {
        float bv = -INFINITY; int bi = INT_MAX; int bs = 0;
        for (int i = t; i < FCAP; i += 256) {
            if (comes_first(sv[i], si[i], bv, bi)) { bv = sv[i]; bi = si[i]; bs = i; }
        }
        int bsv = bs;
        #pragma unroll
        for (int off = 32; off > 0; off >>= 1) {
            const float ov = __shfl_xor(bv, off);
            const int   oi = __shfl_xor(bi, off);
            const int   os = __shfl_xor(bsv, off);
            if (comes_first(ov, oi, bv, bi)) { bv = ov; bi = oi; bsv = os; }
        }
        const int w = t >> 6;
        if ((t & 63) == 0) { wv[w] = bv; wbi[w] = bi; csum[w] = (unsigned)bsv; }
        __syncthreads();
        if (t == 0) {
            float fv = wv[0]; int fi = wbi[0]; int fs = (int)csum[0];
            #pragma unroll
            for (int j = 1; j < 4; ++j)
                if (comes_first(wv[j], wbi[j], fv, fi)) { fv = wv[j]; fi = wbi[j]; fs = (int)csum[j]; }
            out[k] = (float)cand[fi];
            sv[fs] = -INFINITY;
            si[fs] = INT_MAX;
        }
        __syncthreads();
    }
}

extern "C" void kernel_launch(void* const* d_in, const int* in_sizes, int n_in,
                              void* d_out, int out_size, void* d_ws, size_t ws_size,
                              hipStream_t stream) {
    const float* infl  = (const float*)d_in[0];   // [num_cand]
    const float* feats = (const float*)d_in[1];   // [num_nodes, 256]
    const int*   cand  = (const int*)d_in[2];     // [num_cand]
    const float* inj   = (const float*)d_in[3];   // [256]

    const int num_cand = in_sizes[0];

    float* out    = (float*)d_out;          // [0..64): indices-as-f32 (write-only)
    float* scores = (float*)d_out + KSEL;   // [64..): edge scores (write-only)

    unsigned* ws_counts = (unsigned*)d_ws;                // NB2
    float*    ws_v      = (float*)(ws_counts + NB2);      // NB2*BCAP
    int*      ws_i      = (int*)(ws_v + NB2 * BCAP);      // NB2*BCAP
    float*    ws_mirror = (float*)(ws_i + NB2 * BCAP);    // num_cand

    // 1. Edge scores: R6 persistent CPW=4 grid (A/B vs R9-11's CPW=8 one-shot).
    edge_score_kernel<<<NB1, 256, 0, stream>>>(
        infl, feats, cand, inj, scores, ws_mirror, num_cand);

    // 2a. Per-slice local-threshold filter (no fences, no tickets).
    slice_filter_kernel<<<NB2, 256, 0, stream>>>(
        ws_mirror, ws_counts, ws_v, ws_i, num_cand);

    // 2b. Final exact top-64 over ~5K survivors (1 block, tiny data).
    final_topk_kernel<<<1, 256, 0, stream>>>(
        ws_mirror, ws_counts, ws_v, ws_i, cand, out, num_cand);
}

// Round 13
// 46.422 us; speedup vs baseline: 1.5628x; 1.4125x over previous
//
#include <hip/hip_runtime.h>
#include <hip/hip_bf16.h>
#include <float.h>
#include <limits.h>

#define FEAT       256
#define GAMMA_F    0.1f
#define EPS_F      1e-8f
#define KSEL       64        // BUDGET
#define NBUCK      4096      // 12-bit histogram of flipped-float keys
#define KSHIFT     20        // key >> KSHIFT -> bucket
#define NB1        1024      // persistent score blocks (4096 waves = full occupancy)
#define NB3        64        // hist/select blocks
#define CPW        4         // candidates per wave
#define BCAP       64        // per-block survivor region (expected ~2 used)
#define CAP        4096      // final assembly capacity (= NB3 * BCAP)
#define ZWORDS     (NBUCK + NB3 + 3)   // ghist + counts + done + oflow + oflowCnt

// Monotonic float -> uint transform (ascending order preserved).
__device__ __forceinline__ unsigned key_of(float v) {
    unsigned u = __float_as_uint(v);
    return u ^ ((u >> 31) ? 0xFFFFFFFFu : 0x80000000u);
}

__device__ __forceinline__ bool comes_first(float va, int ia, float vb, int ib) {
    return (va > vb) || (va == vb && ia < ib);
}

// ---------------------------------------------------------------------------
// Kernel 1: edge scores. EXACT round-6 kernel (A/A reproduction of the 46.2us
// configuration). Persistent grid (1024 blocks = 4096 waves): each wave
// grid-strides over groups of CPW=4 candidates, 4 independent 1 KB
// row-gathers in flight per iteration. ||inj|| reduced once per wave. Lane 0
// stores the 4 scores as one float4. Also zeroes the K2/K3 workspace (kills
// the memset dispatch). No contended atomics.
// ---------------------------------------------------------------------------
__global__ __launch_bounds__(256) void edge_score_kernel(
    const float* __restrict__ infl,
    const float* __restrict__ feats,
    const int*   __restrict__ cand,
    const float* __restrict__ inj,
    float*       __restrict__ scores,   // d_out + KSEL
    unsigned*    __restrict__ ws_zero,  // ZWORDS words to clear
    int num_cand)
{
    const int gtid = blockIdx.x * blockDim.x + threadIdx.x;
    if (gtid < ZWORDS) ws_zero[gtid] = 0u;   // fire-and-forget

    const int lane    = threadIdx.x & 63;
    const int wid     = gtid >> 6;              // global wave id
    const int nwaves  = NB1 * 4;
    const int ngroups = (num_cand + CPW - 1) / CPW;

    const float4 g = *reinterpret_cast<const float4*>(inj + lane * 4);
    float ng = g.x * g.x + g.y * g.y + g.z * g.z + g.w * g.w;
    #pragma unroll
    for (int off = 32; off > 0; off >>= 1) ng += __shfl_xor(ng, off);
    const float inj_n = fmaxf(sqrtf(ng), EPS_F);

    for (int grp = wid; grp < ngroups; grp += nwaves) {
        const int base   = grp * CPW;
        const int n_here = num_cand - base;   // >= 1

        const int r0 = cand[base];
        const int r1 = (n_here > 1) ? cand[base + 1] : r0;
        const int r2 = (n_here > 2) ? cand[base + 2] : r0;
        const int r3 = (n_here > 3) ? cand[base + 3] : r0;
        const float4 f0 = *reinterpret_cast<const float4*>(feats + (size_t)r0 * FEAT + lane * 4);
        const float4 f1 = *reinterpret_cast<const float4*>(feats + (size_t)r1 * FEAT + lane * 4);
        const float4 f2 = *reinterpret_cast<const float4*>(feats + (size_t)r2 * FEAT + lane * 4);
        const float4 f3 = *reinterpret_cast<const float4*>(feats + (size_t)r3 * FEAT + lane * 4);

        float dot0 = f0.x*g.x + f0.y*g.y + f0.z*g.z + f0.w*g.w;
        float nf0  = f0.x*f0.x + f0.y*f0.y + f0.z*f0.z + f0.w*f0.w;
        float dot1 = f1.x*g.x + f1.y*g.y + f1.z*g.z + f1.w*g.w;
        float nf1  = f1.x*f1.x + f1.y*f1.y + f1.z*f1.z + f1.w*f1.w;
        float dot2 = f2.x*g.x + f2.y*g.y + f2.z*g.z + f2.w*g.w;
        float nf2  = f2.x*f2.x + f2.y*f2.y + f2.z*f2.z + f2.w*f2.w;
        float dot3 = f3.x*g.x + f3.y*g.y + f3.z*g.z + f3.w*g.w;
        float nf3  = f3.x*f3.x + f3.y*f3.y + f3.z*f3.z + f3.w*f3.w;

        #pragma unroll
        for (int off = 32; off > 0; off >>= 1) {
            dot0 += __shfl_xor(dot0, off);  nf0 += __shfl_xor(nf0, off);
            dot1 += __shfl_xor(dot1, off);  nf1 += __shfl_xor(nf1, off);
            dot2 += __shfl_xor(dot2, off);  nf2 += __shfl_xor(nf2, off);
            dot3 += __shfl_xor(dot3, off);  nf3 += __shfl_xor(nf3, off);
        }

        if (lane == 0) {
            const float s0 = infl[base] - GAMMA_F * (dot0 / (fmaxf(sqrtf(nf0), EPS_F) * inj_n));
            if (n_here >= 4) {
                const float s1 = infl[base+1] - GAMMA_F * (dot1 / (fmaxf(sqrtf(nf1), EPS_F) * inj_n));
                const float s2 = infl[base+2] - GAMMA_F * (dot2 / (fmaxf(sqrtf(nf2), EPS_F) * inj_n));
                const float s3 = infl[base+3] - GAMMA_F * (dot3 / (fmaxf(sqrtf(nf3), EPS_F) * inj_n));
                *reinterpret_cast<float4*>(scores + base) = make_float4(s0, s1, s2, s3);
            } else {
                scores[base] = s0;
                if (n_here > 1)
                    scores[base+1] = infl[base+1] - GAMMA_F * (dot1 / (fmaxf(sqrtf(nf1), EPS_F) * inj_n));
                if (n_here > 2)
                    scores[base+2] = infl[base+2] - GAMMA_F * (dot2 / (fmaxf(sqrtf(nf2), EPS_F) * inj_n));
            }
        }
    }
}

// ---------------------------------------------------------------------------
// Kernel 2: 12-bit histogram. LDS pre-aggregation per block, then merge
// nonzero buckets (<=NB3 same-address global atomics, arrivals staggered).
// ---------------------------------------------------------------------------
__global__ __launch_bounds__(256) void hist_kernel(
    const float* __restrict__ scores,
    unsigned*    __restrict__ hist,
    int n)
{
    __shared__ unsigned h[NBUCK];
    for (int i = threadIdx.x; i < NBUCK; i += 256) h[i] = 0;
    __syncthreads();

    const int n4 = n >> 2;
    const float4* s4 = reinterpret_cast<const float4*>(scores);
    for (int g = blockIdx.x * 256 + threadIdx.x; g < n4; g += NB3 * 256) {
        const float4 v = s4[g];
        atomicAdd(&h[key_of(v.x) >> KSHIFT], 1u);
        atomicAdd(&h[key_of(v.y) >> KSHIFT], 1u);
        atomicAdd(&h[key_of(v.z) >> KSHIFT], 1u);
        atomicAdd(&h[key_of(v.w) >> KSHIFT], 1u);
    }
    if (blockIdx.x == 0 && threadIdx.x < (n & 3))
        atomicAdd(&h[key_of(scores[n4 * 4 + threadIdx.x]) >> KSHIFT], 1u);
    __syncthreads();

    for (int i = threadIdx.x; i < NBUCK; i += 256)
        if (h[i]) atomicAdd(&hist[i], h[i]);
}

// ---------------------------------------------------------------------------
// Kernel 3: select. Each block redundantly computes threshold bucket B
// (suffix-scan of the 16 KB L2-hot histogram), compacts its grid-stride
// slice's survivors into a PRIVATE 64-slot region (plain stores + one count
// store). Last-finished block (ticket) prefix-sums the 64 counts, assembles
// survivors in LDS, bitonic-sorts 256 slots (value desc, index asc) for the
// exact top-64.
// ---------------------------------------------------------------------------
__global__ __launch_bounds__(256) void select_kernel(
    const float*    __restrict__ scores,
    const unsigned* __restrict__ hist,
    unsigned*       __restrict__ counts,    // [NB3]
    unsigned*       __restrict__ done,
    unsigned*       __restrict__ oflow,     // flag + spill counter (2 words)
    float*          __restrict__ ws_v,      // [NB3*BCAP]
    int*            __restrict__ ws_i,      // [NB3*BCAP]
    const int*      __restrict__ cand,
    float*          __restrict__ out,       // d_out[0..KSEL)
    int n)
{
    __shared__ unsigned csum[256];
    __shared__ unsigned sB, sCnt;
    __shared__ int      sLast;
    __shared__ unsigned soff[NB3 + 1];
    __shared__ float    sv[CAP];
    __shared__ int      si[CAP];

    const int t   = threadIdx.x;
    const int bid = blockIdx.x;

    // --- 1. threshold bucket B (redundant per block; hist is L2-hot) ---
    {
        const int hi = NBUCK - 16 * t;     // chunk t = buckets [hi-16, hi)
        unsigned s = 0;
        for (int b = hi - 16; b < hi; ++b) s += hist[b];
        csum[t] = s;
    }
    __syncthreads();
    if (t == 0) {
        unsigned cum = 0;
        int tc = 0;
        for (; tc < 256; ++tc) {
            if (cum + csum[tc] >= KSEL) break;
            cum += csum[tc];
        }
        unsigned B = 0;
        if (tc < 256) {
            int b = NBUCK - 16 * tc - 1;
            for (int k = 0; k < 16; ++k, --b) {
                cum += hist[b];
                if (cum >= KSEL) { B = (unsigned)b; break; }
            }
        }
        sB = B;
        sCnt = 0;
    }
    __syncthreads();
    const unsigned B = sB;

    // --- 2. compact slice survivors into the block's private region ---
    const int n4 = n >> 2;
    const float4* s4 = reinterpret_cast<const float4*>(scores);
    for (int g = bid * 256 + t; g < n4; g += NB3 * 256) {
        const float4 v = s4[g];
        const float vv[4] = {v.x, v.y, v.z, v.w};
        #pragma unroll
        for (int j = 0; j < 4; ++j) {
            if ((key_of(vv[j]) >> KSHIFT) >= B) {
                const unsigned p = atomicAdd(&sCnt, 1u);   // LDS atomic
                if (p < BCAP) { ws_v[bid * BCAP + p] = vv[j]; ws_i[bid * BCAP + p] = g * 4 + j; }
            }
        }
    }
    if (bid == 0 && t < (n & 3)) {
        const float v = scores[n4 * 4 + t];
        if ((key_of(v) >> KSHIFT) >= B) {
            const unsigned p = atomicAdd(&sCnt, 1u);
            if (p < BCAP) { ws_v[p] = v; ws_i[p] = n4 * 4 + t; }
        }
    }
    __syncthreads();
    if (t == 0) {
        counts[bid] = min(sCnt, (unsigned)BCAP);
        if (sCnt > BCAP) atomicAdd(&oflow[0], 1u);   // never expected
    }

    // --- ticket: last-finished block assembles + sorts ---
    __threadfence();
    __syncthreads();
    if (t == 0) sLast = (atomicAdd(done, 1u) == (unsigned)(NB3 - 1));
    __syncthreads();
    if (!sLast) return;
    __threadfence();

    int m;
    if (oflow[0] == 0u) {
        // prefix offsets over the 64 region counts
        if (t == 0) {
            unsigned acc = 0;
            #pragma unroll
            for (int r = 0; r < NB3; ++r) { soff[r] = acc; acc += counts[r]; }
            soff[NB3] = acc;
        }
        __syncthreads();
        m = (int)soff[NB3];
        for (int idx = t; idx < NB3 * BCAP; idx += 256) {
            const int r = idx >> 6, j = idx & (BCAP - 1);
            if ((unsigned)j < counts[r]) {
                const unsigned dst = soff[r] + j;
                sv[dst] = ws_v[r * BCAP + j];
                si[dst] = ws_i[r * BCAP + j];
            }
        }
    } else {
        // Safety fallback: solo re-compact into LDS (never expected).
        if (t == 0) sCnt = 0;
        __syncthreads();
        for (int g = t; g < n; g += 256) {
            const float v = scores[g];
            if ((key_of(v) >> KSHIFT) >= B) {
                const unsigned p = atomicAdd(&sCnt, 1u);
                if (p < CAP) { sv[p] = v; si[p] = g; }
            }
        }
        __syncthreads();
        m = (int)min(sCnt, (unsigned)CAP);
    }
    __syncthreads();

    if (m <= 256) {
        // bitonic sort of 256 slots: value desc, index asc (lax.top_k order)
        if (t >= m) { sv[t] = -INFINITY; si[t] = INT_MAX; }
        __syncthreads();
        for (int k = 2; k <= 256; k <<= 1) {
            for (int j = k >> 1; j > 0; j >>= 1) {
                const int p = t ^ j;
                if (p > t) {
                    const float va = sv[t], vb = sv[p];
                    const int   ia = si[t], ib = si[p];
                    const bool asc = ((t & k) == 0);
                    const bool doSwap = asc ? comes_first(vb, ib, va, ia)
                                            : comes_first(va, ia, vb, ib);
                    if (doSwap) { sv[t] = vb; si[t] = ib; sv[p] = va; si[p] = ia; }
                }
                __syncthreads();
            }
        }
        if (t < KSEL) out[t] = (float)cand[si[t]];
        return;
    }

    // Fallback: serial argmax over m <= CAP survivors (never expected).
    __shared__ float wv[4];
    __shared__ int   wbi[4], wbs[4];
    for (int i = t + m; i < CAP; i += 256) { sv[i] = -INFINITY; si[i] = INT_MAX; }
    __syncthreads();
    for (int k = 0; k < KSEL; ++k) {
        float bv = -INFINITY; int bi = INT_MAX; int bs = 0;
        for (int i = t; i < CAP; i += 256) {
            if (comes_first(sv[i], si[i], bv, bi)) { bv = sv[i]; bi = si[i]; bs = i; }
        }
        #pragma unroll
        for (int off = 32; off > 0; off >>= 1) {
            const float ov = __shfl_xor(bv, off);
            const int   oi = __shfl_xor(bi, off);
            const int   os = __shfl_xor(bs, off);
            if (comes_first(ov, oi, bv, bi)) { bv = ov; bi = oi; bs = os; }
        }
        const int w = t >> 6;
        if ((t & 63) == 0) { wv[w] = bv; wbi[w] = bi; wbs[w] = bs; }
        __syncthreads();
        if (t == 0) {
            float fv = wv[0]; int fi = wbi[0]; int fs = wbs[0];
            #pragma unroll
            for (int j = 1; j < 4; ++j)
                if (comes_first(wv[j], wbi[j], fv, fi)) { fv = wv[j]; fi = wbi[j]; fs = wbs[j]; }
            out[k] = (float)cand[fi];
            sv[fs] = -INFINITY;
            si[fs] = INT_MAX;
        }
        __syncthreads();
    }
}

extern "C" void kernel_launch(void* const* d_in, const int* in_sizes, int n_in,
                              void* d_out, int out_size, void* d_ws, size_t ws_size,
                              hipStream_t stream) {
    const float* infl  = (const float*)d_in[0];   // [num_cand]
    const float* feats = (const float*)d_in[1];   // [num_nodes, 256]
    const int*   cand  = (const int*)d_in[2];     // [num_cand]
    const float* inj   = (const float*)d_in[3];   // [256]

    const int num_cand = in_sizes[0];

    float* out    = (float*)d_out;          // [0..64): indices-as-f32
    float* scores = (float*)d_out + KSEL;   // [64..64+num_cand): edge scores

    unsigned* ws_hist   = (unsigned*)d_ws;            // NBUCK
    unsigned* ws_counts = ws_hist + NBUCK;            // NB3
    unsigned* ws_done   = ws_counts + NB3;            // 1
    unsigned* ws_oflow  = ws_done + 1;                // 2
    float*    ws_v      = (float*)(ws_oflow + 2);     // NB3*BCAP
    int*      ws_i      = (int*)(ws_v + NB3 * BCAP);  // NB3*BCAP

    // 1. Edge scores (persistent grid) + workspace zeroing.
    edge_score_kernel<<<NB1, 256, 0, stream>>>(
        infl, feats, cand, inj, scores, ws_hist, num_cand);

    // 2. Histogram (LDS pre-aggregated).
    hist_kernel<<<NB3, 256, 0, stream>>>(scores, ws_hist, num_cand);

    // 3. Threshold + contention-free compact + final top-64.
    select_kernel<<<NB3, 256, 0, stream>>>(
        scores, ws_hist, ws_counts, ws_done, ws_oflow, ws_v, ws_i, cand, out, num_cand);
}